// Round 6
// baseline (281.037 us; speedup 1.0000x reference)
//
#include <hip/hip_runtime.h>
#include <hip/hip_bf16.h>

#define T_TOTAL 200000
#define BATCH 256
#define NBIT 64
#define NCLASS 100
#define TN 128
#define NBLK ((T_TOTAL + TN - 1) / TN)   // 1563

typedef __attribute__((ext_vector_type(8))) short bf16x8;
typedef __attribute__((ext_vector_type(4))) float f32x4;

#define LOG2E 1.4426950408889634f
#define LN2   0.6931471805599453

__device__ __forceinline__ float sgnf(float v) {
    return (v > 0.f) ? 1.f : ((v < 0.f) ? -1.f : 0.f);
}

__device__ __forceinline__ unsigned int pk2(float a, float b) {
    union { __hip_bfloat162 h2; unsigned int ui; } cv;
    cv.h2 = __float22bfloat162_rn(make_float2(a, b));   // low short = a (RNE)
    return cv.ui;
}

// raw HW transcendentals: v_exp_f32 = 2^x, v_log_f32 = log2(x)  (~1 ULP)
__device__ __forceinline__ float hw_exp2(float x) {
    float r; asm("v_exp_f32 %0, %1" : "=v"(r) : "v"(x)); return r;
}
__device__ __forceinline__ float hw_log2(float x) {
    float r; asm("v_log_f32 %0, %1" : "=v"(r) : "v"(x)); return r;
}

// ---------------- kernel A: batch labels (1 block) ---------------------------
__global__ __launch_bounds__(256) void prep_kernel(const float* __restrict__ y,
                                                   int* __restrict__ labB) {
    const int gt = threadIdx.x;                  // 0..255
    const float4* yp = reinterpret_cast<const float4*>(y + gt * NCLASS);
    int l = 0;
    #pragma unroll
    for (int p = 0; p < 25; ++p) {
        float4 v = yp[p];
        if (v.x > 0.5f) l = p * 4;
        if (v.y > 0.5f) l = p * 4 + 1;
        if (v.z > 0.5f) l = p * 4 + 2;
        if (v.w > 0.5f) l = p * 4 + 3;
    }
    labB[gt] = l;
}

// -------- kernel B: fused metric loss (Y-scan + U-stage + MFMA + softplus) ---
// LDS Bt: [col][64 k] shorts, 128B pitch, XOR-swizzled: index = col*64 + (k0 ^ ((col&7)<<3)).
// All Bt accesses are 16B (k0 % 8 == 0) and use the same swizzle -> consistent & conflict-free.
__global__ __launch_bounds__(256, 6) void metric_kernel(const float* __restrict__ u,
                                                        const float* __restrict__ U,
                                                        const float* __restrict__ Y,
                                                        const int* __restrict__ ind,
                                                        const int* __restrict__ labB_g,
                                                        double* __restrict__ partial) {
    __shared__ unsigned short Bt[TN * 64];   // 16 KB
    __shared__ int   labT[TN];
    __shared__ int   labB[BATCH];
    __shared__ float wpart[4];

    const int tid = threadIdx.x;
    const long t0 = (long)blockIdx.x * TN;

    labB[tid] = labB_g[tid];

    // ---- Y label scan for this tile: 100 rows x 32 float4 (one-hot => one writer/col) ----
    {
        const float4* Y4 = reinterpret_cast<const float4*>(Y);
        const int cb = blockIdx.x * 32;              // float4 col base (row len = 50000 f4)
        #pragma unroll
        for (int it = 0; it < 13; ++it) {
            int idx = it * 256 + tid;                // 0..3327; 100*32 = 3200 valid
            if (idx < 3200) {
                int row = idx >> 5;
                int lc4 = idx & 31;
                if (cb + lc4 < 50000) {              // tail-block column guard
                    float4 v = Y4[(long)row * 50000 + cb + lc4];
                    int c = lc4 * 4;
                    if (v.x > 0.5f) labT[c]     = row;
                    if (v.y > 0.5f) labT[c + 1] = row;
                    if (v.z > 0.5f) labT[c + 2] = row;
                    if (v.w > 0.5f) labT[c + 3] = row;
                }
            }
        }
    }

    // ---- stage U tile (bf16, transposed, swizzled) ----
    {
        const int c = tid & 127;
        const int h = tid >> 7;                     // 0..1 (wave-uniform)
        const long t = t0 + c;
        const bool ok = (t < (long)T_TOTAL);
        const int sw = (c & 7) << 3;
        #pragma unroll
        for (int m = 0; m < 4; ++m) {
            unsigned int w[4];
            #pragma unroll
            for (int pp = 0; pp < 4; ++pp) {
                const int kk = h * 32 + m * 8 + 2 * pp;
                float v0 = 0.f, v1 = 0.f;
                if (ok) {
                    v0 = U[(long)kk * T_TOTAL + t];
                    v1 = U[(long)(kk + 1) * T_TOTAL + t];
                }
                w[pp] = pk2(v0, v1);
            }
            const int k0 = h * 32 + m * 8;
            *reinterpret_cast<uint4*>(&Bt[c * 64 + (k0 ^ sw)]) = make_uint4(w[0], w[1], w[2], w[3]);
        }
    }
    __syncthreads();
    // ---- overwrite replaced columns (U_new / Y_new at ind; ind unique) ----
    {
        long c = (long)ind[tid] - t0;
        if (c >= 0 && c < TN) {
            labT[c] = labB[tid];
            const int ci = (int)c;
            const int sw = (ci & 7) << 3;
            #pragma unroll
            for (int m = 0; m < 8; ++m) {
                unsigned int w[4];
                #pragma unroll
                for (int pp = 0; pp < 4; ++pp) {
                    float v0 = u[tid * NBIT + m * 8 + 2 * pp];
                    float v1 = u[tid * NBIT + m * 8 + 2 * pp + 1];
                    w[pp] = pk2(v0, v1);
                }
                *reinterpret_cast<uint4*>(&Bt[ci * 64 + ((m * 8) ^ sw)]) = make_uint4(w[0], w[1], w[2], w[3]);
            }
        }
    }
    __syncthreads();

    // ---- A fragments: bf16(0.5*u) built in-block from u (L2-resident) ----
    const int wid  = tid >> 6;
    const int lane = tid & 63;
    const int lr   = lane & 15;
    const int g4   = lane >> 4;

    bf16x8 afrag[4][2];
    #pragma unroll
    for (int mt = 0; mt < 4; ++mt) {
        #pragma unroll
        for (int kb = 0; kb < 2; ++kb) {
            const int j = wid * 64 + mt * 16 + lr;
            const float* ur = u + j * NBIT + kb * 32 + g4 * 8;
            float4 va = *reinterpret_cast<const float4*>(ur);
            float4 vb = *reinterpret_cast<const float4*>(ur + 4);
            union { bf16x8 v; unsigned int w[4]; } pk;
            pk.w[0] = pk2(0.5f * va.x, 0.5f * va.y);
            pk.w[1] = pk2(0.5f * va.z, 0.5f * va.w);
            pk.w[2] = pk2(0.5f * vb.x, 0.5f * vb.y);
            pk.w[3] = pk2(0.5f * vb.z, 0.5f * vb.w);
            afrag[mt][kb] = pk.v;
        }
    }
    int labR[4][4];
    #pragma unroll
    for (int mt = 0; mt < 4; ++mt)
        #pragma unroll
        for (int e = 0; e < 4; ++e)
            labR[mt][e] = labB[wid * 64 + mt * 16 + g4 * 4 + e];

    // ---- MFMA + fused softplus epilogue (ip pre-scaled by 0.5 in afrag) ----
    float sum2 = 0.f;
    for (int nt = 0; nt < 8; ++nt) {
        if (t0 + nt * 16 >= (long)T_TOTAL) break;   // block-uniform; 200000 % 16 == 0
        const int col = nt * 16 + lr;
        const int sw = (col & 7) << 3;
        union { bf16x8 v; uint4 q; } b0, b1;
        b0.q = *reinterpret_cast<const uint4*>(&Bt[col * 64 + ((g4 * 8) ^ sw)]);
        b1.q = *reinterpret_cast<const uint4*>(&Bt[col * 64 + ((32 + g4 * 8) ^ sw)]);
        const int labc = labT[col];
        #pragma unroll
        for (int mt = 0; mt < 4; ++mt) {
            f32x4 acc4 = {0.f, 0.f, 0.f, 0.f};
            acc4 = __builtin_amdgcn_mfma_f32_16x16x32_bf16(afrag[mt][0], b0.v, acc4, 0, 0, 0);
            acc4 = __builtin_amdgcn_mfma_f32_16x16x32_bf16(afrag[mt][1], b1.v, acc4, 0, 0, 0);
            #pragma unroll
            for (int e = 0; e < 4; ++e) {
                float ip = fminf(fmaxf(acc4[e], -100.f), 50.f);
                float z  = (labc == labR[mt][e]) ? -ip : ip;
                float tt = fmaf(z, LOG2E, LOG2E);    // (1+z)*log2(e), M = 1
                sum2 += hw_log2(1.f + hw_exp2(tt));  // * ln2 applied below
            }
        }
    }
    for (int off = 32; off; off >>= 1) sum2 += __shfl_xor(sum2, off);
    if (lane == 0) wpart[wid] = sum2;
    __syncthreads();
    if (tid == 0)
        partial[blockIdx.x] = (double)(wpart[0] + wpart[1] + wpart[2] + wpart[3]) * LN2;
}

// ---------------- kernel C: DCC center update + quantization loss ------------
__global__ __launch_bounds__(256) void dcc_kernel(const float* __restrict__ u,
                                                  const float* __restrict__ C,
                                                  const int* __restrict__ lab,
                                                  float* __restrict__ out_c,   // d_out+1
                                                  float* __restrict__ quant_out) {
    __shared__ float Q[NCLASS][NBIT];        // 25.6 KB, [class][bit]
    __shared__ float Ct2[NBIT * NCLASS];     // 25.6 KB, [bit][class] == C layout
    __shared__ int   labL[BATCH];
    __shared__ float wq[4];

    const int tid = threadIdx.x;
    const int k   = tid & 63;
    const int g   = tid >> 6;                // 0..3 (wave id)

    labL[tid] = lab[tid];
    for (int o = tid; o < NCLASS * NBIT; o += 256) {
        ((float*)Q)[o] = 0.f;
        Ct2[o] = C[o];                       // coalesced global + LDS
    }
    __syncthreads();

    // Q[i][k] = sum_{j: lab_j==i} b[k][j];  quant = sum (b - u)^2
    // 8-wide load batching breaks the dependent global-latency chain.
    float qloc = 0.f;
    for (int jj = 0; jj < 64; jj += 8) {
        float uu[8]; int lj[8];
        #pragma unroll
        for (int p = 0; p < 8; ++p) {
            int j = g * 64 + jj + p;
            lj[p] = labL[j];                 // wave-uniform broadcast
            uu[p] = u[j * NBIT + k];         // independent, coalesced
        }
        #pragma unroll
        for (int p = 0; p < 8; ++p) {
            float b = sgnf(Ct2[k * NCLASS + lj[p]] + uu[p]);   // MU = 1; original C
            atomicAdd(&Q[lj[p]][k], b);      // exact small ints: order-independent
            float d = b - uu[p];
            qloc += d * d;
        }
    }
    for (int off = 32; off; off >>= 1) qloc += __shfl_xor(qloc, off);
    if ((tid & 63) == 0) wq[g] = qloc;
    __syncthreads();
    if (tid == 0) quant_out[0] = wq[0] + wq[1] + wq[2] + wq[3];

    // sequential cyclic coordinate descent (wave 0); G off-diag == 0 (one-hot)
    if (tid < 64) {
        float total = 0.f;
        for (int i = 0; i < NCLASS; ++i) total += Ct2[k * NCLASS + i];
        float qn = Q[0][k], cn = Ct2[k * NCLASS];
        for (int i = 0; i < NCLASS; ++i) {
            float qc = qn, old = cn;
            if (i + 1 < NCLASS) { qn = Q[i + 1][k]; cn = Ct2[k * NCLASS + i + 1]; }
            float nr = sgnf(qc - (total - old));     // VUL = 1; exact, can be 0.0
            Ct2[k * NCLASS + i] = nr;
            total += nr - old;
        }
    }
    __syncthreads();
    // C_new is already in C's own layout: direct coalesced copy
    for (int o = tid; o < NCLASS * NBIT; o += 256) out_c[o] = Ct2[o];
}

// ---------------- kernel D: finalize loss ------------------------------------
__global__ __launch_bounds__(256) void fin_kernel(const double* __restrict__ partial,
                                                  const float* __restrict__ quant,
                                                  float* __restrict__ out0) {
    __shared__ double wp[4];
    double s = 0.0;
    for (int i = threadIdx.x; i < NBLK; i += 256) s += partial[i];
    for (int off = 32; off; off >>= 1) s += __shfl_xor(s, off);
    if ((threadIdx.x & 63) == 0) wp[threadIdx.x >> 6] = s;
    __syncthreads();
    if (threadIdx.x == 0) {
        double tot = wp[0] + wp[1] + wp[2] + wp[3];
        out0[0] = (float)(tot / ((double)BATCH * (double)T_TOTAL)
                          + 0.5 * ((double)quant[0] / (double)(BATCH * NBIT)));   // ETA=0.5
    }
}

extern "C" void kernel_launch(void* const* d_in, const int* in_sizes, int n_in,
                              void* d_out, int out_size, void* d_ws, size_t ws_size,
                              hipStream_t stream) {
    const float* u   = (const float*)d_in[0];
    const float* y   = (const float*)d_in[1];
    const int*   ind = (const int*)d_in[2];
    const float* U   = (const float*)d_in[3];
    const float* Y   = (const float*)d_in[4];
    const float* C   = (const float*)d_in[5];
    float* out = (float*)d_out;

    // ws layout (all write-before-read each call)
    float*  quant   = (float*)d_ws;                          // 4 B
    int*    labB    = (int*)((char*)d_ws + 64);              // 1 KB
    double* partial = (double*)((char*)d_ws + 2048);         // 12.5 KB

    prep_kernel<<<1, 256, 0, stream>>>(y, labB);
    metric_kernel<<<NBLK, 256, 0, stream>>>(u, U, Y, ind, labB, partial);
    dcc_kernel<<<1, 256, 0, stream>>>(u, C, labB, out + 1, quant);
    fin_kernel<<<1, 256, 0, stream>>>(partial, quant, out);
}

// Round 7
// 232.922 us; speedup vs baseline: 1.2066x; 1.2066x over previous
//
#include <hip/hip_runtime.h>
#include <hip/hip_bf16.h>

#define T_TOTAL 200000
#define BATCH 256
#define NBIT 64
#define NCLASS 100
#define TN 128
#define NBLK ((T_TOTAL + TN - 1) / TN)   // 1563

typedef __attribute__((ext_vector_type(8))) short bf16x8;
typedef __attribute__((ext_vector_type(4))) float f32x4;

#define LOG2E 1.4426950408889634f
#define LN2   0.6931471805599453

// LDS swizzle: short index = col*64 + (k ^ SW(col)); SW touches only k bits 3..5,
// so any 8-short (16B) aligned block stays contiguous. SW spreads tf4=col>>2
// across banks for the float4-vectorized staging writes.
#define SW(c) (((c) << 1) & 0x38)

__device__ __forceinline__ float sgnf(float v) {
    return (v > 0.f) ? 1.f : ((v < 0.f) ? -1.f : 0.f);
}

__device__ __forceinline__ unsigned int pk2(float a, float b) {
    union { __hip_bfloat162 h2; unsigned int ui; } cv;
    cv.h2 = __float22bfloat162_rn(make_float2(a, b));   // low short = a (RNE)
    return cv.ui;
}

// raw HW transcendentals: v_exp_f32 = 2^x, v_log_f32 = log2(x)  (~1 ULP)
__device__ __forceinline__ float hw_exp2(float x) {
    float r; asm("v_exp_f32 %0, %1" : "=v"(r) : "v"(x)); return r;
}
__device__ __forceinline__ float hw_log2(float x) {
    float r; asm("v_log_f32 %0, %1" : "=v"(r) : "v"(x)); return r;
}

// ---------------- kernel A: batch labels (1 block) ---------------------------
__global__ __launch_bounds__(256) void prep_kernel(const float* __restrict__ y,
                                                   int* __restrict__ labB) {
    const int gt = threadIdx.x;                  // 0..255
    const float4* yp = reinterpret_cast<const float4*>(y + gt * NCLASS);
    int l = 0;
    #pragma unroll
    for (int p = 0; p < 25; ++p) {
        float4 v = yp[p];
        if (v.x > 0.5f) l = p * 4;
        if (v.y > 0.5f) l = p * 4 + 1;
        if (v.z > 0.5f) l = p * 4 + 2;
        if (v.w > 0.5f) l = p * 4 + 3;
    }
    labB[gt] = l;
}

// -------- kernel B: fused metric loss (Y-scan + U-stage + MFMA + softplus) ---
__global__ __launch_bounds__(256) void metric_kernel(const float* __restrict__ u,
                                                     const float* __restrict__ U,
                                                     const float* __restrict__ Y,
                                                     const int* __restrict__ ind,
                                                     const int* __restrict__ labB_g,
                                                     double* __restrict__ partial) {
    __shared__ unsigned short Bt[TN * 64];   // 16 KB
    __shared__ int   labT[TN];
    __shared__ int   labB[BATCH];
    __shared__ float wpart[4];

    const int tid = threadIdx.x;
    const long t0 = (long)blockIdx.x * TN;

    labB[tid] = labB_g[tid];

    // ---- Y label scan: 100 rows x 32 float4; register-batched loads ----
    {
        const float4* Y4 = reinterpret_cast<const float4*>(Y);
        const int cb = blockIdx.x * 32;              // float4 col base (row len = 50000 f4)
        float4 vv[13];
        #pragma unroll
        for (int it = 0; it < 13; ++it) {
            const int idx = it * 256 + tid;          // 0..3327; 3200 valid
            const int row = idx >> 5, lc4 = idx & 31;
            const bool okk = (idx < 3200) && (cb + lc4 < 50000);
            vv[it] = okk ? Y4[(long)row * 50000 + cb + lc4]
                         : make_float4(0.f, 0.f, 0.f, 0.f);
        }
        #pragma unroll
        for (int it = 0; it < 13; ++it) {
            const int idx = it * 256 + tid;
            const int row = idx >> 5, c = (idx & 31) * 4;
            float4 v = vv[it];                       // zeros when invalid: never >0.5
            if (v.x > 0.5f) labT[c]     = row;       // one-hot => single writer/col
            if (v.y > 0.5f) labT[c + 1] = row;
            if (v.z > 0.5f) labT[c + 2] = row;
            if (v.w > 0.5f) labT[c + 3] = row;
        }
    }

    // ---- stage U tile (bf16, transposed, swizzled), float4 over t ----
    {
        const float4* U4 = reinterpret_cast<const float4*>(U);
        const int tb4 = (int)(t0 >> 2);              // float4 col base
        #pragma unroll
        for (int it = 0; it < 8; ++it) {
            const int q   = it * 256 + tid;          // 0..2047
            const int k   = q >> 5;                  // 0..63
            const int tf4 = q & 31;                  // local float4 col
            float4 v = make_float4(0.f, 0.f, 0.f, 0.f);
            if (t0 + tf4 * 4 < (long)T_TOTAL)        // T_TOTAL%4==0: no straddle
                v = U4[(long)k * (T_TOTAL / 4) + tb4 + tf4];
            const unsigned int p01 = pk2(v.x, v.y);
            const unsigned int p23 = pk2(v.z, v.w);
            const int c0 = tf4 * 4;
            Bt[(c0    ) * 64 + (k ^ SW(c0    ))] = (unsigned short)(p01);
            Bt[(c0 + 1) * 64 + (k ^ SW(c0 + 1))] = (unsigned short)(p01 >> 16);
            Bt[(c0 + 2) * 64 + (k ^ SW(c0 + 2))] = (unsigned short)(p23);
            Bt[(c0 + 3) * 64 + (k ^ SW(c0 + 3))] = (unsigned short)(p23 >> 16);
        }
    }
    __syncthreads();
    // ---- overwrite replaced columns (U_new / Y_new at ind; ind unique) ----
    {
        long c = (long)ind[tid] - t0;
        if (c >= 0 && c < TN) {
            labT[c] = labB[tid];
            const int ci = (int)c;
            const int sw = SW(ci);
            #pragma unroll
            for (int m = 0; m < 8; ++m) {
                unsigned int w[4];
                #pragma unroll
                for (int pp = 0; pp < 4; ++pp) {
                    float v0 = u[tid * NBIT + m * 8 + 2 * pp];
                    float v1 = u[tid * NBIT + m * 8 + 2 * pp + 1];
                    w[pp] = pk2(v0, v1);
                }
                *reinterpret_cast<uint4*>(&Bt[ci * 64 + ((m * 8) ^ sw)]) = make_uint4(w[0], w[1], w[2], w[3]);
            }
        }
    }
    __syncthreads();

    // ---- A fragments: bf16(0.5*u) built in-block from u (L2-resident) ----
    const int wid  = tid >> 6;
    const int lane = tid & 63;
    const int lr   = lane & 15;
    const int g4   = lane >> 4;

    bf16x8 afrag[4][2];
    #pragma unroll
    for (int mt = 0; mt < 4; ++mt) {
        #pragma unroll
        for (int kb = 0; kb < 2; ++kb) {
            const int j = wid * 64 + mt * 16 + lr;
            const float* ur = u + j * NBIT + kb * 32 + g4 * 8;
            float4 va = *reinterpret_cast<const float4*>(ur);
            float4 vb = *reinterpret_cast<const float4*>(ur + 4);
            union { bf16x8 v; unsigned int w[4]; } pk;
            pk.w[0] = pk2(0.5f * va.x, 0.5f * va.y);
            pk.w[1] = pk2(0.5f * va.z, 0.5f * va.w);
            pk.w[2] = pk2(0.5f * vb.x, 0.5f * vb.y);
            pk.w[3] = pk2(0.5f * vb.z, 0.5f * vb.w);
            afrag[mt][kb] = pk.v;
        }
    }
    int labR[4][4];
    #pragma unroll
    for (int mt = 0; mt < 4; ++mt)
        #pragma unroll
        for (int e = 0; e < 4; ++e)
            labR[mt][e] = labB[wid * 64 + mt * 16 + g4 * 4 + e];

    // ---- MFMA + fused softplus epilogue (ip pre-scaled by 0.5 in afrag) ----
    float sum2 = 0.f;
    for (int nt = 0; nt < 8; ++nt) {
        if (t0 + nt * 16 >= (long)T_TOTAL) break;   // block-uniform; 200000 % 16 == 0
        const int col = nt * 16 + lr;
        const int sw = SW(col);
        union { bf16x8 v; uint4 q; } b0, b1;
        b0.q = *reinterpret_cast<const uint4*>(&Bt[col * 64 + ((g4 * 8) ^ sw)]);
        b1.q = *reinterpret_cast<const uint4*>(&Bt[col * 64 + ((32 + g4 * 8) ^ sw)]);
        const int labc = labT[col];
        #pragma unroll
        for (int mt = 0; mt < 4; ++mt) {
            f32x4 acc4 = {0.f, 0.f, 0.f, 0.f};
            acc4 = __builtin_amdgcn_mfma_f32_16x16x32_bf16(afrag[mt][0], b0.v, acc4, 0, 0, 0);
            acc4 = __builtin_amdgcn_mfma_f32_16x16x32_bf16(afrag[mt][1], b1.v, acc4, 0, 0, 0);
            #pragma unroll
            for (int e = 0; e < 4; ++e) {
                float ip = fminf(fmaxf(acc4[e], -100.f), 50.f);
                float z  = (labc == labR[mt][e]) ? -ip : ip;
                float tt = fmaf(z, LOG2E, LOG2E);    // (1+z)*log2(e), M = 1
                sum2 += hw_log2(1.f + hw_exp2(tt));  // * ln2 applied below
            }
        }
    }
    for (int off = 32; off; off >>= 1) sum2 += __shfl_xor(sum2, off);
    if (lane == 0) wpart[wid] = sum2;
    __syncthreads();
    if (tid == 0)
        partial[blockIdx.x] = (double)(wpart[0] + wpart[1] + wpart[2] + wpart[3]) * LN2;
}

// ---------------- kernel C: DCC center update + quantization loss ------------
__global__ __launch_bounds__(256) void dcc_kernel(const float* __restrict__ u,
                                                  const float* __restrict__ C,
                                                  const int* __restrict__ lab,
                                                  float* __restrict__ out_c,   // d_out+1
                                                  float* __restrict__ quant_out) {
    __shared__ float Q[NCLASS][NBIT];        // 25.6 KB, [class][bit]
    __shared__ float Ct2[NBIT * NCLASS];     // 25.6 KB, [bit][class] == C layout
    __shared__ int   labL[BATCH];
    __shared__ float wq[4];

    const int tid = threadIdx.x;
    const int k   = tid & 63;
    const int g   = tid >> 6;                // 0..3 (wave id)

    labL[tid] = lab[tid];
    for (int o = tid; o < NCLASS * NBIT; o += 256) {
        ((float*)Q)[o] = 0.f;
        Ct2[o] = C[o];                       // coalesced global + LDS
    }
    __syncthreads();

    // Q[i][k] = sum_{j: lab_j==i} b[k][j];  quant = sum (b - u)^2
    float qloc = 0.f;
    for (int jj = 0; jj < 64; jj += 8) {
        float uu[8]; int lj[8];
        #pragma unroll
        for (int p = 0; p < 8; ++p) {
            int j = g * 64 + jj + p;
            lj[p] = labL[j];                 // wave-uniform broadcast
            uu[p] = u[j * NBIT + k];         // independent, coalesced
        }
        #pragma unroll
        for (int p = 0; p < 8; ++p) {
            float b = sgnf(Ct2[k * NCLASS + lj[p]] + uu[p]);   // MU = 1; original C
            atomicAdd(&Q[lj[p]][k], b);      // exact small ints: order-independent
            float d = b - uu[p];
            qloc += d * d;
        }
    }
    for (int off = 32; off; off >>= 1) qloc += __shfl_xor(qloc, off);
    if ((tid & 63) == 0) wq[g] = qloc;
    __syncthreads();
    if (tid == 0) quant_out[0] = wq[0] + wq[1] + wq[2] + wq[3];

    // sequential cyclic coordinate descent (wave 0); G off-diag == 0 (one-hot)
    if (tid < 64) {
        float total = 0.f;
        for (int i = 0; i < NCLASS; ++i) total += Ct2[k * NCLASS + i];
        float qn = Q[0][k], cn = Ct2[k * NCLASS];
        for (int i = 0; i < NCLASS; ++i) {
            float qc = qn, old = cn;
            if (i + 1 < NCLASS) { qn = Q[i + 1][k]; cn = Ct2[k * NCLASS + i + 1]; }
            float nr = sgnf(qc - (total - old));     // VUL = 1; exact, can be 0.0
            Ct2[k * NCLASS + i] = nr;
            total += nr - old;
        }
    }
    __syncthreads();
    // C_new is already in C's own layout: direct coalesced copy
    for (int o = tid; o < NCLASS * NBIT; o += 256) out_c[o] = Ct2[o];
}

// ---------------- kernel D: finalize loss ------------------------------------
__global__ __launch_bounds__(256) void fin_kernel(const double* __restrict__ partial,
                                                  const float* __restrict__ quant,
                                                  float* __restrict__ out0) {
    __shared__ double wp[4];
    double s = 0.0;
    for (int i = threadIdx.x; i < NBLK; i += 256) s += partial[i];
    for (int off = 32; off; off >>= 1) s += __shfl_xor(s, off);
    if ((threadIdx.x & 63) == 0) wp[threadIdx.x >> 6] = s;
    __syncthreads();
    if (threadIdx.x == 0) {
        double tot = wp[0] + wp[1] + wp[2] + wp[3];
        out0[0] = (float)(tot / ((double)BATCH * (double)T_TOTAL)
                          + 0.5 * ((double)quant[0] / (double)(BATCH * NBIT)));   // ETA=0.5
    }
}

extern "C" void kernel_launch(void* const* d_in, const int* in_sizes, int n_in,
                              void* d_out, int out_size, void* d_ws, size_t ws_size,
                              hipStream_t stream) {
    const float* u   = (const float*)d_in[0];
    const float* y   = (const float*)d_in[1];
    const int*   ind = (const int*)d_in[2];
    const float* U   = (const float*)d_in[3];
    const float* Y   = (const float*)d_in[4];
    const float* C   = (const float*)d_in[5];
    float* out = (float*)d_out;

    // ws layout (all write-before-read each call)
    float*  quant   = (float*)d_ws;                          // 4 B
    int*    labB    = (int*)((char*)d_ws + 64);              // 1 KB
    double* partial = (double*)((char*)d_ws + 2048);         // 12.5 KB

    prep_kernel<<<1, 256, 0, stream>>>(y, labB);
    metric_kernel<<<NBLK, 256, 0, stream>>>(u, U, Y, ind, labB, partial);
    dcc_kernel<<<1, 256, 0, stream>>>(u, C, labB, out + 1, quant);
    fin_kernel<<<1, 256, 0, stream>>>(partial, quant, out);
}